// Round 11
// baseline (833.803 us; speedup 1.0000x reference)
//
#include <hip/hip_runtime.h>

#define VOCAB 100000
#define D     300
#define B     256
#define L     1000
#define H     512
#define C     5

#define D4f    (D / 4)      // 75 float4 per row
#define NPH    8            // phases (ranges per XCD octet)
#define RW     1563         // range width: 64 ranges cover VOCAB
#define SELCAP 384          // per-doc octet capacity (mean 125)
#define NBLK   (B / 2 * 8)  // 1024 gather blocks = exactly 4/CU

// ws layout (floats)
#define WS_PARTIAL 0                        // B*8*D = 614400
#define WS_AVG     (B * 8 * D)              // +76800
#define WS_H1      (WS_AVG + B * D)         // +131072
#define WS_H2      (WS_H1 + B * H)          // +131072
#define WS_GBAR    (WS_H2 + B * H)          // +NPH ints

// ---------------------------------------------------------------------------
// K0: zero the phase-barrier counters (ws is not re-poisoned between replays).
// ---------------------------------------------------------------------------
__global__ void zero_bar_kernel(int* __restrict__ gbar) {
  if (threadIdx.x < NPH) gbar[threadIdx.x] = 0;
}

// ---------------------------------------------------------------------------
// K1: phase-aligned XCD-partitioned gather with HARD inter-phase barriers.
// grid = 1024 (4 blocks/CU -> all co-resident by capacity): bid%8 = octet x
// lands on XCD x. Blocks walk ranges x*8+p for p=0..7 in lockstep enforced
// by a bounded-spin grid barrier, so each XCD's L2 holds <=2 ranges
// (3.8 MB <= 4 MB) and the ~2.77x row reuse becomes L2 hits.
// Bounded spin (never deadlocks): timeout degrades to slow-but-correct.
// ---------------------------------------------------------------------------
__global__ __launch_bounds__(320) void gather_phased_kernel(
    const float* __restrict__ emb, const int* __restrict__ docs,
    float* __restrict__ partial, int* __restrict__ gbar) {
  const int bid = blockIdx.x;
  const int x = bid & 7;            // XCD / vocab octet
  const int j = bid >> 3;           // doc pair
  const int t = threadIdx.x;
  const int g = t / 80;             // row group 0..3
  const int lane = t - g * 80;      // 0..79 (75 active)

  __shared__ int    s_raw[2][L];         // 8000 B
  __shared__ int    s_sel[2][SELCAP];    // 3072 B
  __shared__ int    s_cnt[2][NPH];
  __shared__ int    s_off[2][NPH + 1];
  __shared__ float4 sred[4][2][D4f];     // 9600 B

  // Stage both docs' raw indices.
  for (int i = t; i < 2 * L; i += 320) {
    const int dd = i < L ? 0 : 1;
    const int ii = dd ? i - L : i;
    s_raw[dd][ii] = docs[(size_t)(j * 2 + dd) * L + ii];
  }
  if (t < 2 * NPH) s_cnt[t >> 3][t & 7] = 0;
  __syncthreads();

  // Count per-phase sizes (octet x only).
  for (int i = t; i < 2 * L; i += 320) {
    const int dd = i < L ? 0 : 1;
    const int idx = s_raw[dd][dd ? i - L : i];
    const int r = idx / RW;
    if ((r & 7) == x) atomicAdd(&s_cnt[dd][r >> 3], 1);
  }
  __syncthreads();
  if (t < 2) {
    int acc = 0;
#pragma unroll
    for (int p = 0; p < NPH; ++p) { s_off[t][p] = acc; acc += s_cnt[t][p]; }
    s_off[t][NPH] = acc;
  }
  __syncthreads();
  if (t < 2 * NPH) s_cnt[t >> 3][t & 7] = 0;
  __syncthreads();

  // Scatter selected indices, bucketed by phase.
  for (int i = t; i < 2 * L; i += 320) {
    const int dd = i < L ? 0 : 1;
    const int idx = s_raw[dd][dd ? i - L : i];
    const int r = idx / RW;
    if ((r & 7) == x) {
      const int pos = s_off[dd][r >> 3] + atomicAdd(&s_cnt[dd][r >> 3], 1);
      s_sel[dd][pos] = idx;
    }
  }
  __syncthreads();

  // Phase loop with hard alignment.
  float4 a0 = make_float4(0.f, 0.f, 0.f, 0.f);
  float4 a1 = make_float4(0.f, 0.f, 0.f, 0.f);
  for (int p = 0; p < NPH; ++p) {
    if (lane < D4f) {
      {
        const int s = s_off[0][p], e = s_off[0][p + 1];
        for (int i = s + g; i < e; i += 4) {
          const float4 v = reinterpret_cast<const float4*>(
              emb + (size_t)s_sel[0][i] * D)[lane];
          a0.x += v.x; a0.y += v.y; a0.z += v.z; a0.w += v.w;
        }
      }
      {
        const int s = s_off[1][p], e = s_off[1][p + 1];
        for (int i = s + g; i < e; i += 4) {
          const float4 v = reinterpret_cast<const float4*>(
              emb + (size_t)s_sel[1][i] * D)[lane];
          a1.x += v.x; a1.y += v.y; a1.z += v.z; a1.w += v.w;
        }
      }
    }
    if (p < NPH - 1) {
      __syncthreads();
      if (t == 0) {
        __hip_atomic_fetch_add(&gbar[p], 1, __ATOMIC_ACQ_REL,
                               __HIP_MEMORY_SCOPE_AGENT);
        int spins = 0;
        while (__hip_atomic_load(&gbar[p], __ATOMIC_ACQUIRE,
                                 __HIP_MEMORY_SCOPE_AGENT) < NBLK) {
          if (++spins > 20000) break;   // deadlock-proof: degrade, not hang
          __builtin_amdgcn_s_sleep(16);
        }
      }
      __syncthreads();
    }
  }
  if (lane < D4f) {
    sred[g][0][lane] = a0;
    sred[g][1][lane] = a1;
  }
  __syncthreads();

  if (t < 2 * D4f) {
    const int dd = t / D4f, c4 = t - dd * D4f;
    float ax = 0.f, ay = 0.f, az = 0.f, aw = 0.f;
#pragma unroll
    for (int gg = 0; gg < 4; ++gg) {
      const float4 v = sred[gg][dd][c4];
      ax += v.x; ay += v.y; az += v.z; aw += v.w;
    }
    reinterpret_cast<float4*>(partial +
                              (size_t)((j * 2 + dd) * 8 + x) * D)[c4] =
        make_float4(ax, ay, az, aw);
  }
}

// ---------------------------------------------------------------------------
// K2: avg[b] = (sum of 8 octet-partials) / len[b].
// ---------------------------------------------------------------------------
__global__ __launch_bounds__(128) void avg_kernel(
    const float* __restrict__ partial, const int* __restrict__ dlen,
    float* __restrict__ avg) {
  const int b = blockIdx.x;
  const int t = threadIdx.x;
  if (t < D4f) {
    const float4* p =
        reinterpret_cast<const float4*>(partial) + (size_t)b * 8 * D4f + t;
    float4 v[8];
#pragma unroll
    for (int xx = 0; xx < 8; ++xx) v[xx] = p[xx * D4f];
    float ax = 0.f, ay = 0.f, az = 0.f, aw = 0.f;
#pragma unroll
    for (int xx = 0; xx < 8; ++xx) {
      ax += v[xx].x; ay += v[xx].y; az += v[xx].z; aw += v[xx].w;
    }
    const float inv = 1.f / (float)dlen[b];
    reinterpret_cast<float4*>(avg + (size_t)b * D)[t] =
        make_float4(ax * inv, ay * inv, az * inv, aw * inv);
  }
}

// ---------------------------------------------------------------------------
// K3: h1 = relu(avg @ W1 + b1). LDS-staged weights (proven structure).
// ---------------------------------------------------------------------------
__global__ __launch_bounds__(1024) void l1_kernel(
    const float* __restrict__ avg, const float* __restrict__ W1,
    const float* __restrict__ b1, float* __restrict__ h1) {
  const int dq = blockIdx.x;
  const int cq = blockIdx.y;
  const int t = threadIdx.x;

  __shared__ float4 s_avg[16][D4f];
  __shared__ float  s_w[D][32];
  __shared__ float  s_comb[8][16][32];

  for (int o = t; o < D * 8; o += 1024) {
    const int k = o >> 3, c4 = o & 7;
    *reinterpret_cast<float4*>(&s_w[k][c4 * 4]) =
        *reinterpret_cast<const float4*>(W1 + (size_t)k * H + cq * 32 + c4 * 4);
  }
  for (int o = t; o < 16 * D4f; o += 1024) {
    const int doc = o / D4f, c4 = o - doc * D4f;
    s_avg[doc][c4] =
        reinterpret_cast<const float4*>(avg + (size_t)(dq * 16 + doc) * D)[c4];
  }
  __syncthreads();

  {
    const int doc = t & 15;
    const int cg = (t >> 4) & 7;
    const int ks = t >> 7;
    const int nf4 = (ks < 3) ? 10 : 9;
    const int o4 = (ks < 3) ? 10 * ks : 30 + 9 * (ks - 3);
    float ax = 0.f, ay = 0.f, az = 0.f, aw = 0.f;
    for (int j = 0; j < nf4; ++j) {
      const float4 x4 = s_avg[doc][o4 + j];
      const int k = 4 * (o4 + j);
      const float4 w0 = *reinterpret_cast<const float4*>(&s_w[k + 0][cg * 4]);
      const float4 w1 = *reinterpret_cast<const float4*>(&s_w[k + 1][cg * 4]);
      const float4 w2 = *reinterpret_cast<const float4*>(&s_w[k + 2][cg * 4]);
      const float4 w3 = *reinterpret_cast<const float4*>(&s_w[k + 3][cg * 4]);
      ax += x4.x * w0.x + x4.y * w1.x + x4.z * w2.x + x4.w * w3.x;
      ay += x4.x * w0.y + x4.y * w1.y + x4.z * w2.y + x4.w * w3.y;
      az += x4.x * w0.z + x4.y * w1.z + x4.z * w2.z + x4.w * w3.z;
      aw += x4.x * w0.w + x4.y * w1.w + x4.z * w2.w + x4.w * w3.w;
    }
    *reinterpret_cast<float4*>(&s_comb[ks][doc][cg * 4]) =
        make_float4(ax, ay, az, aw);
  }
  __syncthreads();

  if (t < 512) {
    const int dd = t >> 5, col = t & 31;
    float v = b1[cq * 32 + col];
#pragma unroll
    for (int s = 0; s < 8; ++s) v += s_comb[s][dd][col];
    h1[(size_t)(dq * 16 + dd) * H + cq * 32 + col] = fmaxf(v, 0.f);
  }
}

// ---------------------------------------------------------------------------
// K4: h2 = relu(h1 @ W2 + b2).
// ---------------------------------------------------------------------------
__global__ __launch_bounds__(1024) void l2_kernel(
    const float* __restrict__ h1, const float* __restrict__ W2,
    const float* __restrict__ b2, float* __restrict__ h2) {
  const int dq = blockIdx.x;
  const int cq = blockIdx.y;
  const int t = threadIdx.x;

  __shared__ float4 s_x[16][H / 4];
  __shared__ float  s_w[H][32];
  __shared__ float  s_comb[8][16][32];

  for (int o = t; o < H * 8; o += 1024) {
    const int k = o >> 3, c4 = o & 7;
    *reinterpret_cast<float4*>(&s_w[k][c4 * 4]) =
        *reinterpret_cast<const float4*>(W2 + (size_t)k * H + cq * 32 + c4 * 4);
  }
  for (int o = t; o < 16 * (H / 4); o += 1024) {
    const int doc = o >> 7, c4 = o & 127;
    s_x[doc][c4] =
        reinterpret_cast<const float4*>(h1 + (size_t)(dq * 16 + doc) * H)[c4];
  }
  __syncthreads();

  {
    const int doc = t & 15;
    const int cg = (t >> 4) & 7;
    const int ks = t >> 7;
    float ax = 0.f, ay = 0.f, az = 0.f, aw = 0.f;
    for (int j = 0; j < 16; ++j) {
      const int kk = ks * 16 + j;
      const float4 x4 = s_x[doc][kk];
      const int k = 4 * kk;
      const float4 w0 = *reinterpret_cast<const float4*>(&s_w[k + 0][cg * 4]);
      const float4 w1 = *reinterpret_cast<const float4*>(&s_w[k + 1][cg * 4]);
      const float4 w2 = *reinterpret_cast<const float4*>(&s_w[k + 2][cg * 4]);
      const float4 w3 = *reinterpret_cast<const float4*>(&s_w[k + 3][cg * 4]);
      ax += x4.x * w0.x + x4.y * w1.x + x4.z * w2.x + x4.w * w3.x;
      ay += x4.x * w0.y + x4.y * w1.y + x4.z * w2.y + x4.w * w3.y;
      az += x4.x * w0.z + x4.y * w1.z + x4.z * w2.z + x4.w * w3.z;
      aw += x4.x * w0.w + x4.y * w1.w + x4.z * w2.w + x4.w * w3.w;
    }
    *reinterpret_cast<float4*>(&s_comb[ks][doc][cg * 4]) =
        make_float4(ax, ay, az, aw);
  }
  __syncthreads();

  if (t < 512) {
    const int dd = t >> 5, col = t & 31;
    float v = b2[cq * 32 + col];
#pragma unroll
    for (int s = 0; s < 8; ++s) v += s_comb[s][dd][col];
    h2[(size_t)(dq * 16 + dd) * H + cq * 32 + col] = fmaxf(v, 0.f);
  }
}

// ---------------------------------------------------------------------------
// K5: out = h2 @ W3 + b3.
// ---------------------------------------------------------------------------
__global__ __launch_bounds__(64) void head_kernel(
    const float* __restrict__ h2, const float* __restrict__ W3,
    const float* __restrict__ b3, float* __restrict__ out) {
  const int b = blockIdx.x;
  const int l = threadIdx.x;
  float acc[C] = {0.f, 0.f, 0.f, 0.f, 0.f};
#pragma unroll
  for (int i = 0; i < H / 64; ++i) {
    const int h = i * 64 + l;
    const float v = h2[(size_t)b * H + h];
#pragma unroll
    for (int c = 0; c < C; ++c) acc[c] += v * W3[h * C + c];
  }
#pragma unroll
  for (int c = 0; c < C; ++c) {
    float a = acc[c];
#pragma unroll
    for (int off = 32; off > 0; off >>= 1) a += __shfl_down(a, off);
    if (l == 0) out[b * C + c] = a + b3[c];
  }
}

// ---------------------------------------------------------------------------
extern "C" void kernel_launch(void* const* d_in, const int* in_sizes, int n_in,
                              void* d_out, int out_size, void* d_ws,
                              size_t ws_size, hipStream_t stream) {
  const float* emb  = (const float*)d_in[0];
  const float* W1   = (const float*)d_in[1];
  const float* b1   = (const float*)d_in[2];
  const float* W2   = (const float*)d_in[3];
  const float* b2   = (const float*)d_in[4];
  const float* W3   = (const float*)d_in[5];
  const float* b3   = (const float*)d_in[6];
  const int*   docs = (const int*)d_in[7];
  const int*   dlen = (const int*)d_in[8];
  float* out = (float*)d_out;

  float* ws = (float*)d_ws;
  float* partial = ws + WS_PARTIAL;
  float* avg = ws + WS_AVG;
  float* h1  = ws + WS_H1;
  float* h2  = ws + WS_H2;
  int*   gbar = (int*)(ws + WS_GBAR);

  zero_bar_kernel<<<1, 64, 0, stream>>>(gbar);
  gather_phased_kernel<<<NBLK, 320, 0, stream>>>(emb, docs, partial, gbar);
  avg_kernel<<<B, 128, 0, stream>>>(partial, dlen, avg);
  dim3 gl(16, 16);
  l1_kernel<<<gl, 1024, 0, stream>>>(avg, W1, b1, h1);
  l2_kernel<<<gl, 1024, 0, stream>>>(h1, W2, b2, h2);
  head_kernel<<<B, 64, 0, stream>>>(h2, W3, b3, out);
}

// Round 12
// 163.743 us; speedup vs baseline: 5.0922x; 5.0922x over previous
//
#include <hip/hip_runtime.h>

#define VOCAB 100000
#define D     300
#define B     256
#define L     1000
#define H     512
#define C     5

#define D4f    (D / 4)      // 75 float4 per row
#define NPH    8            // phases (ranges per XCD octet)
#define RW     1563         // range width: 64 ranges cover VOCAB
#define SELCAP 384          // per-doc octet capacity (mean 125)
#define NBLK   (B / 2 * 8)  // 1024 gather blocks
#define NBLKX  128          // blocks per XCD (arrivals per barrier)

// ws layout (floats)
#define WS_PARTIAL 0                        // B*8*D = 614400
#define WS_AVG     (B * 8 * D)              // +76800
#define WS_H1      (WS_AVG + B * D)         // +131072
#define WS_H2      (WS_H1 + B * H)          // +131072
#define WS_GBAR    (WS_H2 + B * H)          // 8 XCDs x 8 phases x 64-int stride

// ---------------------------------------------------------------------------
// K0: zero the per-XCD phase-barrier counters (16 KB).
// ---------------------------------------------------------------------------
__global__ void zero_bar_kernel(int* __restrict__ gbar) {
  for (int i = threadIdx.x; i < 8 * 8 * 64; i += 1024) gbar[i] = 0;
}

// ---------------------------------------------------------------------------
// K1: phase-aligned XCD-partitioned gather, PER-XCD relaxed barriers.
// bid%8 = octet x lands on XCD x (round-robin dispatch). XCD x's 128 blocks
// walk ranges x+8p for p=0..7; a relaxed per-XCD barrier (128 arrivals, own
// cache line) keeps the live set <=2 ranges = 3.8 MB <= 4 MB L2, so the
// ~2.8x row reuse is L2-hit (R11 proof: FETCH 165->59 MB).
// No data crosses the barrier -> relaxed atomics; timeout skips ALL
// remaining barriers (perf hint only, never a correctness dependency).
// ---------------------------------------------------------------------------
__global__ __launch_bounds__(320) void gather_phased_kernel(
    const float* __restrict__ emb, const int* __restrict__ docs,
    float* __restrict__ partial, int* __restrict__ gbar) {
  const int bid = blockIdx.x;
  const int x = bid & 7;            // XCD / vocab octet
  const int j = bid >> 3;           // doc pair
  const int t = threadIdx.x;
  const int g = t / 80;             // row group 0..3
  const int lane = t - g * 80;      // 0..79 (75 active)

  __shared__ int    s_raw[2][L];         // 8000 B
  __shared__ int    s_sel[2][SELCAP];    // 3072 B
  __shared__ int    s_cnt[2][NPH];
  __shared__ int    s_off[2][NPH + 1];
  __shared__ int    s_skip;
  __shared__ float4 sred[4][2][D4f];     // 9600 B

  // Stage both docs' raw indices.
  for (int i = t; i < 2 * L; i += 320) {
    const int dd = i < L ? 0 : 1;
    const int ii = dd ? i - L : i;
    s_raw[dd][ii] = docs[(size_t)(j * 2 + dd) * L + ii];
  }
  if (t < 2 * NPH) s_cnt[t >> 3][t & 7] = 0;
  if (t == 0) s_skip = 0;
  __syncthreads();

  // Count per-phase sizes (octet x only).
  for (int i = t; i < 2 * L; i += 320) {
    const int dd = i < L ? 0 : 1;
    const int idx = s_raw[dd][dd ? i - L : i];
    const int r = idx / RW;
    if ((r & 7) == x) atomicAdd(&s_cnt[dd][r >> 3], 1);
  }
  __syncthreads();
  if (t < 2) {
    int acc = 0;
#pragma unroll
    for (int p = 0; p < NPH; ++p) { s_off[t][p] = acc; acc += s_cnt[t][p]; }
    s_off[t][NPH] = acc;
  }
  __syncthreads();
  if (t < 2 * NPH) s_cnt[t >> 3][t & 7] = 0;
  __syncthreads();

  // Scatter selected indices, bucketed by phase.
  for (int i = t; i < 2 * L; i += 320) {
    const int dd = i < L ? 0 : 1;
    const int idx = s_raw[dd][dd ? i - L : i];
    const int r = idx / RW;
    if ((r & 7) == x) {
      const int pos = s_off[dd][r >> 3] + atomicAdd(&s_cnt[dd][r >> 3], 1);
      s_sel[dd][pos] = idx;
    }
  }
  __syncthreads();

  // Phase loop with per-XCD alignment.
  float4 a0 = make_float4(0.f, 0.f, 0.f, 0.f);
  float4 a1 = make_float4(0.f, 0.f, 0.f, 0.f);
  for (int p = 0; p < NPH; ++p) {
    if (lane < D4f) {
      {
        const int s = s_off[0][p], e = s_off[0][p + 1];
        for (int i = s + g; i < e; i += 4) {
          const float4 v = reinterpret_cast<const float4*>(
              emb + (size_t)s_sel[0][i] * D)[lane];
          a0.x += v.x; a0.y += v.y; a0.z += v.z; a0.w += v.w;
        }
      }
      {
        const int s = s_off[1][p], e = s_off[1][p + 1];
        for (int i = s + g; i < e; i += 4) {
          const float4 v = reinterpret_cast<const float4*>(
              emb + (size_t)s_sel[1][i] * D)[lane];
          a1.x += v.x; a1.y += v.y; a1.z += v.z; a1.w += v.w;
        }
      }
    }
    if (p < NPH - 1) {
      __syncthreads();
      if (t == 0 && !s_skip) {
        int* ctr = &gbar[(x * 8 + p) * 64];   // own 256B line per (xcd,phase)
        __hip_atomic_fetch_add(ctr, 1, __ATOMIC_RELAXED,
                               __HIP_MEMORY_SCOPE_AGENT);
        int spins = 0;
        while (__hip_atomic_load(ctr, __ATOMIC_RELAXED,
                                 __HIP_MEMORY_SCOPE_AGENT) < NBLKX) {
          if (++spins > 400) { s_skip = 1; break; }  // skip all remaining
          __builtin_amdgcn_s_sleep(8);
        }
      }
      __syncthreads();
    }
  }
  if (lane < D4f) {
    sred[g][0][lane] = a0;
    sred[g][1][lane] = a1;
  }
  __syncthreads();

  if (t < 2 * D4f) {
    const int dd = t / D4f, c4 = t - dd * D4f;
    float ax = 0.f, ay = 0.f, az = 0.f, aw = 0.f;
#pragma unroll
    for (int gg = 0; gg < 4; ++gg) {
      const float4 v = sred[gg][dd][c4];
      ax += v.x; ay += v.y; az += v.z; aw += v.w;
    }
    reinterpret_cast<float4*>(partial +
                              (size_t)((j * 2 + dd) * 8 + x) * D)[c4] =
        make_float4(ax, ay, az, aw);
  }
}

// ---------------------------------------------------------------------------
// K2: avg[b] = (sum of 8 octet-partials) / len[b].
// ---------------------------------------------------------------------------
__global__ __launch_bounds__(128) void avg_kernel(
    const float* __restrict__ partial, const int* __restrict__ dlen,
    float* __restrict__ avg) {
  const int b = blockIdx.x;
  const int t = threadIdx.x;
  if (t < D4f) {
    const float4* p =
        reinterpret_cast<const float4*>(partial) + (size_t)b * 8 * D4f + t;
    float4 v[8];
#pragma unroll
    for (int xx = 0; xx < 8; ++xx) v[xx] = p[xx * D4f];
    float ax = 0.f, ay = 0.f, az = 0.f, aw = 0.f;
#pragma unroll
    for (int xx = 0; xx < 8; ++xx) {
      ax += v[xx].x; ay += v[xx].y; az += v[xx].z; aw += v[xx].w;
    }
    const float inv = 1.f / (float)dlen[b];
    reinterpret_cast<float4*>(avg + (size_t)b * D)[t] =
        make_float4(ax * inv, ay * inv, az * inv, aw * inv);
  }
}

// ---------------------------------------------------------------------------
// K3: h1 = relu(avg @ W1 + b1). LDS-staged weights (proven structure).
// ---------------------------------------------------------------------------
__global__ __launch_bounds__(1024) void l1_kernel(
    const float* __restrict__ avg, const float* __restrict__ W1,
    const float* __restrict__ b1, float* __restrict__ h1) {
  const int dq = blockIdx.x;
  const int cq = blockIdx.y;
  const int t = threadIdx.x;

  __shared__ float4 s_avg[16][D4f];
  __shared__ float  s_w[D][32];
  __shared__ float  s_comb[8][16][32];

  for (int o = t; o < D * 8; o += 1024) {
    const int k = o >> 3, c4 = o & 7;
    *reinterpret_cast<float4*>(&s_w[k][c4 * 4]) =
        *reinterpret_cast<const float4*>(W1 + (size_t)k * H + cq * 32 + c4 * 4);
  }
  for (int o = t; o < 16 * D4f; o += 1024) {
    const int doc = o / D4f, c4 = o - doc * D4f;
    s_avg[doc][c4] =
        reinterpret_cast<const float4*>(avg + (size_t)(dq * 16 + doc) * D)[c4];
  }
  __syncthreads();

  {
    const int doc = t & 15;
    const int cg = (t >> 4) & 7;
    const int ks = t >> 7;
    const int nf4 = (ks < 3) ? 10 : 9;
    const int o4 = (ks < 3) ? 10 * ks : 30 + 9 * (ks - 3);
    float ax = 0.f, ay = 0.f, az = 0.f, aw = 0.f;
    for (int j = 0; j < nf4; ++j) {
      const float4 x4 = s_avg[doc][o4 + j];
      const int k = 4 * (o4 + j);
      const float4 w0 = *reinterpret_cast<const float4*>(&s_w[k + 0][cg * 4]);
      const float4 w1 = *reinterpret_cast<const float4*>(&s_w[k + 1][cg * 4]);
      const float4 w2 = *reinterpret_cast<const float4*>(&s_w[k + 2][cg * 4]);
      const float4 w3 = *reinterpret_cast<const float4*>(&s_w[k + 3][cg * 4]);
      ax += x4.x * w0.x + x4.y * w1.x + x4.z * w2.x + x4.w * w3.x;
      ay += x4.x * w0.y + x4.y * w1.y + x4.z * w2.y + x4.w * w3.y;
      az += x4.x * w0.z + x4.y * w1.z + x4.z * w2.z + x4.w * w3.z;
      aw += x4.x * w0.w + x4.y * w1.w + x4.z * w2.w + x4.w * w3.w;
    }
    *reinterpret_cast<float4*>(&s_comb[ks][doc][cg * 4]) =
        make_float4(ax, ay, az, aw);
  }
  __syncthreads();

  if (t < 512) {
    const int dd = t >> 5, col = t & 31;
    float v = b1[cq * 32 + col];
#pragma unroll
    for (int s = 0; s < 8; ++s) v += s_comb[s][dd][col];
    h1[(size_t)(dq * 16 + dd) * H + cq * 32 + col] = fmaxf(v, 0.f);
  }
}

// ---------------------------------------------------------------------------
// K4: h2 = relu(h1 @ W2 + b2).
// ---------------------------------------------------------------------------
__global__ __launch_bounds__(1024) void l2_kernel(
    const float* __restrict__ h1, const float* __restrict__ W2,
    const float* __restrict__ b2, float* __restrict__ h2) {
  const int dq = blockIdx.x;
  const int cq = blockIdx.y;
  const int t = threadIdx.x;

  __shared__ float4 s_x[16][H / 4];
  __shared__ float  s_w[H][32];
  __shared__ float  s_comb[8][16][32];

  for (int o = t; o < H * 8; o += 1024) {
    const int k = o >> 3, c4 = o & 7;
    *reinterpret_cast<float4*>(&s_w[k][c4 * 4]) =
        *reinterpret_cast<const float4*>(W2 + (size_t)k * H + cq * 32 + c4 * 4);
  }
  for (int o = t; o < 16 * (H / 4); o += 1024) {
    const int doc = o >> 7, c4 = o & 127;
    s_x[doc][c4] =
        reinterpret_cast<const float4*>(h1 + (size_t)(dq * 16 + doc) * H)[c4];
  }
  __syncthreads();

  {
    const int doc = t & 15;
    const int cg = (t >> 4) & 7;
    const int ks = t >> 7;
    float ax = 0.f, ay = 0.f, az = 0.f, aw = 0.f;
    for (int j = 0; j < 16; ++j) {
      const int kk = ks * 16 + j;
      const float4 x4 = s_x[doc][kk];
      const int k = 4 * kk;
      const float4 w0 = *reinterpret_cast<const float4*>(&s_w[k + 0][cg * 4]);
      const float4 w1 = *reinterpret_cast<const float4*>(&s_w[k + 1][cg * 4]);
      const float4 w2 = *reinterpret_cast<const float4*>(&s_w[k + 2][cg * 4]);
      const float4 w3 = *reinterpret_cast<const float4*>(&s_w[k + 3][cg * 4]);
      ax += x4.x * w0.x + x4.y * w1.x + x4.z * w2.x + x4.w * w3.x;
      ay += x4.x * w0.y + x4.y * w1.y + x4.z * w2.y + x4.w * w3.y;
      az += x4.x * w0.z + x4.y * w1.z + x4.z * w2.z + x4.w * w3.z;
      aw += x4.x * w0.w + x4.y * w1.w + x4.z * w2.w + x4.w * w3.w;
    }
    *reinterpret_cast<float4*>(&s_comb[ks][doc][cg * 4]) =
        make_float4(ax, ay, az, aw);
  }
  __syncthreads();

  if (t < 512) {
    const int dd = t >> 5, col = t & 31;
    float v = b2[cq * 32 + col];
#pragma unroll
    for (int s = 0; s < 8; ++s) v += s_comb[s][dd][col];
    h2[(size_t)(dq * 16 + dd) * H + cq * 32 + col] = fmaxf(v, 0.f);
  }
}

// ---------------------------------------------------------------------------
// K5: out = h2 @ W3 + b3.
// ---------------------------------------------------------------------------
__global__ __launch_bounds__(64) void head_kernel(
    const float* __restrict__ h2, const float* __restrict__ W3,
    const float* __restrict__ b3, float* __restrict__ out) {
  const int b = blockIdx.x;
  const int l = threadIdx.x;
  float acc[C] = {0.f, 0.f, 0.f, 0.f, 0.f};
#pragma unroll
  for (int i = 0; i < H / 64; ++i) {
    const int h = i * 64 + l;
    const float v = h2[(size_t)b * H + h];
#pragma unroll
    for (int c = 0; c < C; ++c) acc[c] += v * W3[h * C + c];
  }
#pragma unroll
  for (int c = 0; c < C; ++c) {
    float a = acc[c];
#pragma unroll
    for (int off = 32; off > 0; off >>= 1) a += __shfl_down(a, off);
    if (l == 0) out[b * C + c] = a + b3[c];
  }
}

// ---------------------------------------------------------------------------
extern "C" void kernel_launch(void* const* d_in, const int* in_sizes, int n_in,
                              void* d_out, int out_size, void* d_ws,
                              size_t ws_size, hipStream_t stream) {
  const float* emb  = (const float*)d_in[0];
  const float* W1   = (const float*)d_in[1];
  const float* b1   = (const float*)d_in[2];
  const float* W2   = (const float*)d_in[3];
  const float* b2   = (const float*)d_in[4];
  const float* W3   = (const float*)d_in[5];
  const float* b3   = (const float*)d_in[6];
  const int*   docs = (const int*)d_in[7];
  const int*   dlen = (const int*)d_in[8];
  float* out = (float*)d_out;

  float* ws = (float*)d_ws;
  float* partial = ws + WS_PARTIAL;
  float* avg = ws + WS_AVG;
  float* h1  = ws + WS_H1;
  float* h2  = ws + WS_H2;
  int*   gbar = (int*)(ws + WS_GBAR);

  zero_bar_kernel<<<1, 1024, 0, stream>>>(gbar);
  gather_phased_kernel<<<NBLK, 320, 0, stream>>>(emb, docs, partial, gbar);
  avg_kernel<<<B, 128, 0, stream>>>(partial, dlen, avg);
  dim3 gl(16, 16);
  l1_kernel<<<gl, 1024, 0, stream>>>(avg, W1, b1, h1);
  l2_kernel<<<gl, 1024, 0, stream>>>(h1, W2, b2, h2);
  head_kernel<<<B, 64, 0, stream>>>(h2, W3, b3, out);
}

// Round 13
// 66.182 us; speedup vs baseline: 12.5986x; 2.4741x over previous
//
#include <hip/hip_runtime.h>

#define VOCAB 100000
#define D     300
#define B     256
#define L     1000
#define H     512
#define C     5

#define D4f    (D / 4)      // 75 float4 per row
#define NPH    8            // soft phases (ranges per XCD octet)
#define RW     1563         // range width: 64 ranges cover VOCAB
#define SELCAP 384          // per-doc octet capacity (mean 125, +24 sigma)
#define NBLK   (B / 2 * 8)  // 1024 gather blocks

// ws layout (floats)
#define WS_AVG 0                 // B*D = 76800 (atomic-accumulated sums -> /len in l1)
#define WS_H1  (B * D)           // B*H = 131072

// ---------------------------------------------------------------------------
// K0: zero the avg accumulator and out (both atomically accumulated).
// ---------------------------------------------------------------------------
__global__ __launch_bounds__(256) void zero_kernel(float* __restrict__ avg,
                                                   float* __restrict__ out) {
  const int i = blockIdx.x * 256 + threadIdx.x;
  if (i < B * D) avg[i] = 0.f;
  if (i < B * C) out[i] = 0.f;
}

// ---------------------------------------------------------------------------
// K1: XCD-partitioned gather, sync-free soft phase alignment (R10 structure,
// proven 60.7 us total). bid%8 = vocab octet x lands on XCD x; each block
// walks its sorted ranges in order, giving statistical L2 locality without
// barriers (R11/R12 showed hard sync costs ~100 us — abandoned).
// Finish: coalesced atomicAdd into avg[doc] (removes partial round-trip +
// avg dispatch).
// ---------------------------------------------------------------------------
__global__ __launch_bounds__(320) void gather_phased_kernel(
    const float* __restrict__ emb, const int* __restrict__ docs,
    float* __restrict__ avg) {
  const int bid = blockIdx.x;
  const int x = bid & 7;            // XCD / vocab octet
  const int j = bid >> 3;           // doc pair
  const int t = threadIdx.x;
  const int g = t / 80;             // row group 0..3
  const int lane = t - g * 80;      // 0..79 (75 active)

  __shared__ int    s_raw[2][L];         // 8000 B
  __shared__ int    s_sel[2][SELCAP];    // 3072 B
  __shared__ int    s_cnt[2][NPH];
  __shared__ int    s_off[2][NPH + 1];
  __shared__ float4 sred[4][2][D4f];     // 9600 B

  for (int i = t; i < 2 * L; i += 320) {
    const int dd = i < L ? 0 : 1;
    const int ii = dd ? i - L : i;
    s_raw[dd][ii] = docs[(size_t)(j * 2 + dd) * L + ii];
  }
  if (t < 2 * NPH) s_cnt[t >> 3][t & 7] = 0;
  __syncthreads();

  for (int i = t; i < 2 * L; i += 320) {
    const int dd = i < L ? 0 : 1;
    const int idx = s_raw[dd][dd ? i - L : i];
    const int r = idx / RW;
    if ((r & 7) == x) atomicAdd(&s_cnt[dd][r >> 3], 1);
  }
  __syncthreads();
  if (t < 2) {
    int acc = 0;
#pragma unroll
    for (int p = 0; p < NPH; ++p) { s_off[t][p] = acc; acc += s_cnt[t][p]; }
    s_off[t][NPH] = acc;
  }
  __syncthreads();
  if (t < 2 * NPH) s_cnt[t >> 3][t & 7] = 0;
  __syncthreads();

  for (int i = t; i < 2 * L; i += 320) {
    const int dd = i < L ? 0 : 1;
    const int idx = s_raw[dd][dd ? i - L : i];
    const int r = idx / RW;
    if ((r & 7) == x) {
      const int pos = s_off[dd][r >> 3] + atomicAdd(&s_cnt[dd][r >> 3], 1);
      s_sel[dd][pos] = idx;
    }
  }
  __syncthreads();

  // Walk ranges in order (soft alignment across blocks on the same XCD).
  float4 a0 = make_float4(0.f, 0.f, 0.f, 0.f);
  float4 a1 = make_float4(0.f, 0.f, 0.f, 0.f);
  if (lane < D4f) {
    for (int p = 0; p < NPH; ++p) {
      {
        const int s = s_off[0][p], e = s_off[0][p + 1];
        for (int i = s + g; i < e; i += 4) {
          const float4 v = reinterpret_cast<const float4*>(
              emb + (size_t)s_sel[0][i] * D)[lane];
          a0.x += v.x; a0.y += v.y; a0.z += v.z; a0.w += v.w;
        }
      }
      {
        const int s = s_off[1][p], e = s_off[1][p + 1];
        for (int i = s + g; i < e; i += 4) {
          const float4 v = reinterpret_cast<const float4*>(
              emb + (size_t)s_sel[1][i] * D)[lane];
          a1.x += v.x; a1.y += v.y; a1.z += v.z; a1.w += v.w;
        }
      }
    }
    sred[g][0][lane] = a0;
    sred[g][1][lane] = a1;
  }
  __syncthreads();

  if (t < 2 * D4f) {
    const int dd = t / D4f, c4 = t - dd * D4f;
    float ax = 0.f, ay = 0.f, az = 0.f, aw = 0.f;
#pragma unroll
    for (int gg = 0; gg < 4; ++gg) {
      const float4 v = sred[gg][dd][c4];
      ax += v.x; ay += v.y; az += v.z; aw += v.w;
    }
    float* dst = avg + (size_t)(j * 2 + dd) * D + c4 * 4;
    atomicAdd(dst + 0, ax);
    atomicAdd(dst + 1, ay);
    atomicAdd(dst + 2, az);
    atomicAdd(dst + 3, aw);
  }
}

// ---------------------------------------------------------------------------
// K2: h1 = relu((sum/len) @ W1 + b1). /len folded into LDS staging.
// grid (16 doc-tiles, 16 col-tiles) x 1024; LDS-staged weights (proven).
// ---------------------------------------------------------------------------
__global__ __launch_bounds__(1024) void l1_kernel(
    const float* __restrict__ avg, const int* __restrict__ dlen,
    const float* __restrict__ W1, const float* __restrict__ b1,
    float* __restrict__ h1) {
  const int dq = blockIdx.x;
  const int cq = blockIdx.y;
  const int t = threadIdx.x;

  __shared__ float  s_inv[16];
  __shared__ float4 s_avg[16][D4f];
  __shared__ float  s_w[D][32];
  __shared__ float  s_comb[8][16][32];

  if (t < 16) s_inv[t] = 1.f / (float)dlen[dq * 16 + t];
  __syncthreads();

  for (int o = t; o < D * 8; o += 1024) {
    const int k = o >> 3, c4 = o & 7;
    *reinterpret_cast<float4*>(&s_w[k][c4 * 4]) =
        *reinterpret_cast<const float4*>(W1 + (size_t)k * H + cq * 32 + c4 * 4);
  }
  for (int o = t; o < 16 * D4f; o += 1024) {
    const int doc = o / D4f, c4 = o - doc * D4f;
    const float4 v =
        reinterpret_cast<const float4*>(avg + (size_t)(dq * 16 + doc) * D)[c4];
    const float inv = s_inv[doc];
    s_avg[doc][c4] = make_float4(v.x * inv, v.y * inv, v.z * inv, v.w * inv);
  }
  __syncthreads();

  {
    const int doc = t & 15;
    const int cg = (t >> 4) & 7;
    const int ks = t >> 7;
    const int nf4 = (ks < 3) ? 10 : 9;
    const int o4 = (ks < 3) ? 10 * ks : 30 + 9 * (ks - 3);
    float ax = 0.f, ay = 0.f, az = 0.f, aw = 0.f;
    for (int j = 0; j < nf4; ++j) {
      const float4 x4 = s_avg[doc][o4 + j];
      const int k = 4 * (o4 + j);
      const float4 w0 = *reinterpret_cast<const float4*>(&s_w[k + 0][cg * 4]);
      const float4 w1 = *reinterpret_cast<const float4*>(&s_w[k + 1][cg * 4]);
      const float4 w2 = *reinterpret_cast<const float4*>(&s_w[k + 2][cg * 4]);
      const float4 w3 = *reinterpret_cast<const float4*>(&s_w[k + 3][cg * 4]);
      ax += x4.x * w0.x + x4.y * w1.x + x4.z * w2.x + x4.w * w3.x;
      ay += x4.x * w0.y + x4.y * w1.y + x4.z * w2.y + x4.w * w3.y;
      az += x4.x * w0.z + x4.y * w1.z + x4.z * w2.z + x4.w * w3.z;
      aw += x4.x * w0.w + x4.y * w1.w + x4.z * w2.w + x4.w * w3.w;
    }
    *reinterpret_cast<float4*>(&s_comb[ks][doc][cg * 4]) =
        make_float4(ax, ay, az, aw);
  }
  __syncthreads();

  if (t < 512) {
    const int dd = t >> 5, col = t & 31;
    float v = b1[cq * 32 + col];
#pragma unroll
    for (int s = 0; s < 8; ++s) v += s_comb[s][dd][col];
    h1[(size_t)(dq * 16 + dd) * H + cq * 32 + col] = fmaxf(v, 0.f);
  }
}

// ---------------------------------------------------------------------------
// K3: h2 tile = relu(h1 @ W2 + b2) in LDS, then head partial folded in:
// out[doc][c] += sum over this block's 32 cols (atomicAdd, 80/block).
// b3 added by cq==0 blocks only. Removes the h2 buffer and head dispatch.
// ---------------------------------------------------------------------------
__global__ __launch_bounds__(1024) void l2_head_kernel(
    const float* __restrict__ h1, const float* __restrict__ W2,
    const float* __restrict__ b2, const float* __restrict__ W3,
    const float* __restrict__ b3, float* __restrict__ out) {
  const int dq = blockIdx.x;
  const int cq = blockIdx.y;
  const int t = threadIdx.x;

  __shared__ float4 s_x[16][H / 4];          // 32768 B
  __shared__ float  s_w[H][32];              // 65536 B
  __shared__ float  s_comb[8][16][32];       // 16384 B
  __shared__ float  s_h2t[16][32];           // 2048 B

  for (int o = t; o < H * 8; o += 1024) {
    const int k = o >> 3, c4 = o & 7;
    *reinterpret_cast<float4*>(&s_w[k][c4 * 4]) =
        *reinterpret_cast<const float4*>(W2 + (size_t)k * H + cq * 32 + c4 * 4);
  }
  for (int o = t; o < 16 * (H / 4); o += 1024) {
    const int doc = o >> 7, c4 = o & 127;
    s_x[doc][c4] =
        reinterpret_cast<const float4*>(h1 + (size_t)(dq * 16 + doc) * H)[c4];
  }
  __syncthreads();

  {
    const int doc = t & 15;
    const int cg = (t >> 4) & 7;
    const int ks = t >> 7;
    float ax = 0.f, ay = 0.f, az = 0.f, aw = 0.f;
    for (int j = 0; j < 16; ++j) {
      const int kk = ks * 16 + j;
      const float4 x4 = s_x[doc][kk];
      const int k = 4 * kk;
      const float4 w0 = *reinterpret_cast<const float4*>(&s_w[k + 0][cg * 4]);
      const float4 w1 = *reinterpret_cast<const float4*>(&s_w[k + 1][cg * 4]);
      const float4 w2 = *reinterpret_cast<const float4*>(&s_w[k + 2][cg * 4]);
      const float4 w3 = *reinterpret_cast<const float4*>(&s_w[k + 3][cg * 4]);
      ax += x4.x * w0.x + x4.y * w1.x + x4.z * w2.x + x4.w * w3.x;
      ay += x4.x * w0.y + x4.y * w1.y + x4.z * w2.y + x4.w * w3.y;
      az += x4.x * w0.z + x4.y * w1.z + x4.z * w2.z + x4.w * w3.z;
      aw += x4.x * w0.w + x4.y * w1.w + x4.z * w2.w + x4.w * w3.w;
    }
    *reinterpret_cast<float4*>(&s_comb[ks][doc][cg * 4]) =
        make_float4(ax, ay, az, aw);
  }
  __syncthreads();

  if (t < 512) {
    const int dd = t >> 5, col = t & 31;
    float v = b2[cq * 32 + col];
#pragma unroll
    for (int s = 0; s < 8; ++s) v += s_comb[s][dd][col];
    s_h2t[dd][col] = fmaxf(v, 0.f);
  }
  __syncthreads();

  if (t < 16 * C) {
    const int doc = t / C;
    const int c = t - doc * C;
    float a = (cq == 0) ? b3[c] : 0.f;
#pragma unroll
    for (int k = 0; k < 32; ++k) a += s_h2t[doc][k] * W3[(cq * 32 + k) * C + c];
    atomicAdd(&out[(size_t)(dq * 16 + doc) * C + c], a);
  }
}

// ---------------------------------------------------------------------------
extern "C" void kernel_launch(void* const* d_in, const int* in_sizes, int n_in,
                              void* d_out, int out_size, void* d_ws,
                              size_t ws_size, hipStream_t stream) {
  const float* emb  = (const float*)d_in[0];
  const float* W1   = (const float*)d_in[1];
  const float* b1   = (const float*)d_in[2];
  const float* W2   = (const float*)d_in[3];
  const float* b2   = (const float*)d_in[4];
  const float* W3   = (const float*)d_in[5];
  const float* b3   = (const float*)d_in[6];
  const int*   docs = (const int*)d_in[7];
  const int*   dlen = (const int*)d_in[8];
  float* out = (float*)d_out;

  float* ws = (float*)d_ws;
  float* avg = ws + WS_AVG;
  float* h1  = ws + WS_H1;

  zero_kernel<<<(B * D + 255) / 256, 256, 0, stream>>>(avg, out);
  gather_phased_kernel<<<NBLK, 320, 0, stream>>>(emb, docs, avg);
  dim3 gl(16, 16);
  l1_kernel<<<gl, 1024, 0, stream>>>(avg, dlen, W1, b1, h1);
  l2_head_kernel<<<gl, 1024, 0, stream>>>(h1, W2, b2, W3, b3, out);
}

// Round 14
// 65.676 us; speedup vs baseline: 12.6957x; 1.0077x over previous
//
#include <hip/hip_runtime.h>

#define VOCAB 100000
#define D     300
#define B     256
#define L     1000
#define H     512
#define C     5

#define D4f    (D / 4)      // 75 float4 per row
#define NPH    16           // phases per XCD octet (range = 0.94 MB)
#define RW     782          // range width: 128 ranges cover VOCAB (782*128=100096)
#define SELCAP 384          // per-doc octet capacity (mean 125, +23 sigma)
#define NBLK   (B / 2 * 8)  // 1024 gather blocks = 4/CU

// ws layout (floats)
#define WS_PARTIAL 0                        // B*8*D = 614400
#define WS_AVG     (B * 8 * D)              // +76800
#define WS_H1      (WS_AVG + B * D)         // +131072

// ---------------------------------------------------------------------------
// K0: zero out (accumulated atomically by l2_head). 1280 floats.
// ---------------------------------------------------------------------------
__global__ __launch_bounds__(256) void zero_out_kernel(float* __restrict__ out) {
  const int i = blockIdx.x * 256 + threadIdx.x;
  if (i < B * C) out[i] = 0.f;
}

// ---------------------------------------------------------------------------
// K1: XCD-partitioned gather, sync-free soft phase alignment (R10 structure,
// proven). bid%8 = vocab octet x -> XCD x via round-robin dispatch. Each
// block buckets its 2 docs' octet-x indices into 16 phases (range 0.94 MB)
// and walks them in order. Statistical lockstep keeps each XCD's live set
// ~ range + 2*drift ~ 2.6 MB <= 4 MB L2 (R10's 8 phases: 3.5 MB, marginal).
// Plain stores to partial (R13 showed atomic-avg costs +5 us).
// ---------------------------------------------------------------------------
__global__ __launch_bounds__(320) void gather_phased_kernel(
    const float* __restrict__ emb, const int* __restrict__ docs,
    float* __restrict__ partial) {
  const int bid = blockIdx.x;
  const int x = bid & 7;            // XCD / vocab octet
  const int j = bid >> 3;           // doc pair
  const int t = threadIdx.x;
  const int g = t / 80;             // row group 0..3
  const int lane = t - g * 80;      // 0..79 (75 active)

  __shared__ int    s_raw[2][L];         // 8000 B
  __shared__ int    s_sel[2][SELCAP];    // 3072 B
  __shared__ int    s_cnt[2][NPH];
  __shared__ int    s_off[2][NPH + 1];
  __shared__ float4 sred[4][2][D4f];     // 9600 B

  for (int i = t; i < 2 * L; i += 320) {
    const int dd = i < L ? 0 : 1;
    const int ii = dd ? i - L : i;
    s_raw[dd][ii] = docs[(size_t)(j * 2 + dd) * L + ii];
  }
  if (t < 2 * NPH) s_cnt[t / NPH][t % NPH] = 0;
  __syncthreads();

  // Count per-phase sizes (octet x only). r in [0,128): octet r&7, phase r>>3.
  for (int i = t; i < 2 * L; i += 320) {
    const int dd = i < L ? 0 : 1;
    const int idx = s_raw[dd][dd ? i - L : i];
    const int r = idx / RW;
    if ((r & 7) == x) atomicAdd(&s_cnt[dd][r >> 3], 1);
  }
  __syncthreads();
  if (t < 2) {
    int acc = 0;
#pragma unroll
    for (int p = 0; p < NPH; ++p) { s_off[t][p] = acc; acc += s_cnt[t][p]; }
    s_off[t][NPH] = acc;
  }
  __syncthreads();
  if (t < 2 * NPH) s_cnt[t / NPH][t % NPH] = 0;
  __syncthreads();

  for (int i = t; i < 2 * L; i += 320) {
    const int dd = i < L ? 0 : 1;
    const int idx = s_raw[dd][dd ? i - L : i];
    const int r = idx / RW;
    if ((r & 7) == x) {
      const int pos = s_off[dd][r >> 3] + atomicAdd(&s_cnt[dd][r >> 3], 1);
      s_sel[dd][pos] = idx;
    }
  }
  __syncthreads();

  // Walk the 16 ranges in order (soft alignment across the XCD's blocks).
  float4 a0 = make_float4(0.f, 0.f, 0.f, 0.f);
  float4 a1 = make_float4(0.f, 0.f, 0.f, 0.f);
  if (lane < D4f) {
    for (int p = 0; p < NPH; ++p) {
      {
        const int s = s_off[0][p], e = s_off[0][p + 1];
        for (int i = s + g; i < e; i += 4) {
          const float4 v = reinterpret_cast<const float4*>(
              emb + (size_t)s_sel[0][i] * D)[lane];
          a0.x += v.x; a0.y += v.y; a0.z += v.z; a0.w += v.w;
        }
      }
      {
        const int s = s_off[1][p], e = s_off[1][p + 1];
        for (int i = s + g; i < e; i += 4) {
          const float4 v = reinterpret_cast<const float4*>(
              emb + (size_t)s_sel[1][i] * D)[lane];
          a1.x += v.x; a1.y += v.y; a1.z += v.z; a1.w += v.w;
        }
      }
    }
    sred[g][0][lane] = a0;
    sred[g][1][lane] = a1;
  }
  __syncthreads();

  if (t < 2 * D4f) {
    const int dd = t / D4f, c4 = t - dd * D4f;
    float ax = 0.f, ay = 0.f, az = 0.f, aw = 0.f;
#pragma unroll
    for (int gg = 0; gg < 4; ++gg) {
      const float4 v = sred[gg][dd][c4];
      ax += v.x; ay += v.y; az += v.z; aw += v.w;
    }
    reinterpret_cast<float4*>(partial +
                              (size_t)((j * 2 + dd) * 8 + x) * D)[c4] =
        make_float4(ax, ay, az, aw);
  }
}

// ---------------------------------------------------------------------------
// K2: avg[b] = (sum of 8 octet-partials) / len[b]. (R10 proven.)
// ---------------------------------------------------------------------------
__global__ __launch_bounds__(128) void avg_kernel(
    const float* __restrict__ partial, const int* __restrict__ dlen,
    float* __restrict__ avg) {
  const int b = blockIdx.x;
  const int t = threadIdx.x;
  if (t < D4f) {
    const float4* p =
        reinterpret_cast<const float4*>(partial) + (size_t)b * 8 * D4f + t;
    float4 v[8];
#pragma unroll
    for (int xx = 0; xx < 8; ++xx) v[xx] = p[xx * D4f];
    float ax = 0.f, ay = 0.f, az = 0.f, aw = 0.f;
#pragma unroll
    for (int xx = 0; xx < 8; ++xx) {
      ax += v[xx].x; ay += v[xx].y; az += v[xx].z; aw += v[xx].w;
    }
    const float inv = 1.f / (float)dlen[b];
    reinterpret_cast<float4*>(avg + (size_t)b * D)[t] =
        make_float4(ax * inv, ay * inv, az * inv, aw * inv);
  }
}

// ---------------------------------------------------------------------------
// K3: h1 = relu(avg @ W1 + b1). LDS-staged weights (proven structure).
// ---------------------------------------------------------------------------
__global__ __launch_bounds__(1024) void l1_kernel(
    const float* __restrict__ avg, const float* __restrict__ W1,
    const float* __restrict__ b1, float* __restrict__ h1) {
  const int dq = blockIdx.x;
  const int cq = blockIdx.y;
  const int t = threadIdx.x;

  __shared__ float4 s_avg[16][D4f];
  __shared__ float  s_w[D][32];
  __shared__ float  s_comb[8][16][32];

  for (int o = t; o < D * 8; o += 1024) {
    const int k = o >> 3, c4 = o & 7;
    *reinterpret_cast<float4*>(&s_w[k][c4 * 4]) =
        *reinterpret_cast<const float4*>(W1 + (size_t)k * H + cq * 32 + c4 * 4);
  }
  for (int o = t; o < 16 * D4f; o += 1024) {
    const int doc = o / D4f, c4 = o - doc * D4f;
    s_avg[doc][c4] =
        reinterpret_cast<const float4*>(avg + (size_t)(dq * 16 + doc) * D)[c4];
  }
  __syncthreads();

  {
    const int doc = t & 15;
    const int cg = (t >> 4) & 7;
    const int ks = t >> 7;
    const int nf4 = (ks < 3) ? 10 : 9;
    const int o4 = (ks < 3) ? 10 * ks : 30 + 9 * (ks - 3);
    float ax = 0.f, ay = 0.f, az = 0.f, aw = 0.f;
    for (int j = 0; j < nf4; ++j) {
      const float4 x4 = s_avg[doc][o4 + j];
      const int k = 4 * (o4 + j);
      const float4 w0 = *reinterpret_cast<const float4*>(&s_w[k + 0][cg * 4]);
      const float4 w1 = *reinterpret_cast<const float4*>(&s_w[k + 1][cg * 4]);
      const float4 w2 = *reinterpret_cast<const float4*>(&s_w[k + 2][cg * 4]);
      const float4 w3 = *reinterpret_cast<const float4*>(&s_w[k + 3][cg * 4]);
      ax += x4.x * w0.x + x4.y * w1.x + x4.z * w2.x + x4.w * w3.x;
      ay += x4.x * w0.y + x4.y * w1.y + x4.z * w2.y + x4.w * w3.y;
      az += x4.x * w0.z + x4.y * w1.z + x4.z * w2.z + x4.w * w3.z;
      aw += x4.x * w0.w + x4.y * w1.w + x4.z * w2.w + x4.w * w3.w;
    }
    *reinterpret_cast<float4*>(&s_comb[ks][doc][cg * 4]) =
        make_float4(ax, ay, az, aw);
  }
  __syncthreads();

  if (t < 512) {
    const int dd = t >> 5, col = t & 31;
    float v = b1[cq * 32 + col];
#pragma unroll
    for (int s = 0; s < 8; ++s) v += s_comb[s][dd][col];
    h1[(size_t)(dq * 16 + dd) * H + cq * 32 + col] = fmaxf(v, 0.f);
  }
}

// ---------------------------------------------------------------------------
// K4: h2 tile = relu(h1 @ W2 + b2) in LDS; head partial folded in via 80
// atomics/block into out (20K total — negligible; R13's regression was the
// 614K avg atomics, now reverted).
// ---------------------------------------------------------------------------
__global__ __launch_bounds__(1024) void l2_head_kernel(
    const float* __restrict__ h1, const float* __restrict__ W2,
    const float* __restrict__ b2, const float* __restrict__ W3,
    const float* __restrict__ b3, float* __restrict__ out) {
  const int dq = blockIdx.x;
  const int cq = blockIdx.y;
  const int t = threadIdx.x;

  __shared__ float4 s_x[16][H / 4];          // 32768 B
  __shared__ float  s_w[H][32];              // 65536 B
  __shared__ float  s_comb[8][16][32];       // 16384 B
  __shared__ float  s_h2t[16][32];           // 2048 B

  for (int o = t; o < H * 8; o += 1024) {
    const int k = o >> 3, c4 = o & 7;
    *reinterpret_cast<float4*>(&s_w[k][c4 * 4]) =
        *reinterpret_cast<const float4*>(W2 + (size_t)k * H + cq * 32 + c4 * 4);
  }
  for (int o = t; o < 16 * (H / 4); o += 1024) {
    const int doc = o >> 7, c4 = o & 127;
    s_x[doc][c4] =
        reinterpret_cast<const float4*>(h1 + (size_t)(dq * 16 + doc) * H)[c4];
  }
  __syncthreads();

  {
    const int doc = t & 15;
    const int cg = (t >> 4) & 7;
    const int ks = t >> 7;
    float ax = 0.f, ay = 0.f, az = 0.f, aw = 0.f;
    for (int j = 0; j < 16; ++j) {
      const int kk = ks * 16 + j;
      const float4 x4 = s_x[doc][kk];
      const int k = 4 * kk;
      const float4 w0 = *reinterpret_cast<const float4*>(&s_w[k + 0][cg * 4]);
      const float4 w1 = *reinterpret_cast<const float4*>(&s_w[k + 1][cg * 4]);
      const float4 w2 = *reinterpret_cast<const float4*>(&s_w[k + 2][cg * 4]);
      const float4 w3 = *reinterpret_cast<const float4*>(&s_w[k + 3][cg * 4]);
      ax += x4.x * w0.x + x4.y * w1.x + x4.z * w2.x + x4.w * w3.x;
      ay += x4.x * w0.y + x4.y * w1.y + x4.z * w2.y + x4.w * w3.y;
      az += x4.x * w0.z + x4.y * w1.z + x4.z * w2.z + x4.w * w3.z;
      aw += x4.x * w0.w + x4.y * w1.w + x4.z * w2.w + x4.w * w3.w;
    }
    *reinterpret_cast<float4*>(&s_comb[ks][doc][cg * 4]) =
        make_float4(ax, ay, az, aw);
  }
  __syncthreads();

  if (t < 512) {
    const int dd = t >> 5, col = t & 31;
    float v = b2[cq * 32 + col];
#pragma unroll
    for (int s = 0; s < 8; ++s) v += s_comb[s][dd][col];
    s_h2t[dd][col] = fmaxf(v, 0.f);
  }
  __syncthreads();

  if (t < 16 * C) {
    const int doc = t / C;
    const int c = t - doc * C;
    float a = (cq == 0) ? b3[c] : 0.f;
#pragma unroll
    for (int k = 0; k < 32; ++k) a += s_h2t[doc][k] * W3[(cq * 32 + k) * C + c];
    atomicAdd(&out[(size_t)(dq * 16 + doc) * C + c], a);
  }
}

// ---------------------------------------------------------------------------
extern "C" void kernel_launch(void* const* d_in, const int* in_sizes, int n_in,
                              void* d_out, int out_size, void* d_ws,
                              size_t ws_size, hipStream_t stream) {
  const float* emb  = (const float*)d_in[0];
  const float* W1   = (const float*)d_in[1];
  const float* b1   = (const float*)d_in[2];
  const float* W2   = (const float*)d_in[3];
  const float* b2   = (const float*)d_in[4];
  const float* W3   = (const float*)d_in[5];
  const float* b3   = (const float*)d_in[6];
  const int*   docs = (const int*)d_in[7];
  const int*   dlen = (const int*)d_in[8];
  float* out = (float*)d_out;

  float* ws = (float*)d_ws;
  float* partial = ws + WS_PARTIAL;
  float* avg = ws + WS_AVG;
  float* h1  = ws + WS_H1;

  zero_out_kernel<<<(B * C + 255) / 256, 256, 0, stream>>>(out);
  gather_phased_kernel<<<NBLK, 320, 0, stream>>>(emb, docs, partial);
  avg_kernel<<<B, 128, 0, stream>>>(partial, dlen, avg);
  dim3 gl(16, 16);
  l1_kernel<<<gl, 1024, 0, stream>>>(avg, W1, b1, h1);
  l2_head_kernel<<<gl, 1024, 0, stream>>>(h1, W2, b2, W3, b3, out);
}

// Round 15
// 60.638 us; speedup vs baseline: 13.7504x; 1.0831x over previous
//
#include <hip/hip_runtime.h>

#define VOCAB 100000
#define D     300
#define B     256
#define L     1000
#define H     512
#define C     5

#define D4f    (D / 4)      // 75 float4 per row
#define NPH    8            // phases (ranges per XCD octet)
#define RW     1563         // range width: 64 ranges cover VOCAB
#define SELCAP 384          // per-doc octet capacity (mean 125, +24 sigma)

// ws layout (floats)
#define WS_PARTIAL 0                        // B*8*D = 614400
#define WS_AVG     (B * 8 * D)              // +76800
#define WS_H1      (WS_AVG + B * D)         // +131072
#define WS_H2      (WS_H1 + B * H)          // +131072 -> ~3.8 MB

// ---------------------------------------------------------------------------
// K1: phase-aligned XCD-partitioned gather (R10, best measured: 60.7 us).
// bid%8 = vocab octet x -> XCD x via round-robin dispatch. Each block
// self-buckets its 2 docs' octet-x indices by range-phase and walks phases
// 0..7 in order. Sync-free statistical lockstep keeps each XCD's live set
// near L2 size; hard barriers (R11/R12) cost ~100 us — abandoned.
// ---------------------------------------------------------------------------
__global__ __launch_bounds__(320) void gather_phased_kernel(
    const float* __restrict__ emb, const int* __restrict__ docs,
    float* __restrict__ partial) {
  const int bid = blockIdx.x;
  const int x = bid & 7;            // XCD / vocab octet
  const int j = bid >> 3;           // doc pair
  const int t = threadIdx.x;
  const int g = t / 80;             // row group 0..3
  const int lane = t - g * 80;      // 0..79 (75 active)

  __shared__ int    s_raw[2][L];         // 8000 B
  __shared__ int    s_sel[2][SELCAP];    // 3072 B
  __shared__ int    s_cnt[2][NPH];
  __shared__ int    s_off[2][NPH + 1];
  __shared__ float4 sred[4][2][D4f];     // 9600 B

  // Stage both docs' raw indices.
  for (int i = t; i < 2 * L; i += 320) {
    const int dd = i < L ? 0 : 1;
    const int ii = dd ? i - L : i;
    s_raw[dd][ii] = docs[(size_t)(j * 2 + dd) * L + ii];
  }
  if (t < 2 * NPH) s_cnt[t >> 3][t & 7] = 0;
  __syncthreads();

  // Count per-phase sizes (octet x only).
  for (int i = t; i < 2 * L; i += 320) {
    const int dd = i < L ? 0 : 1;
    const int idx = s_raw[dd][dd ? i - L : i];
    const int r = idx / RW;
    if ((r & 7) == x) atomicAdd(&s_cnt[dd][r >> 3], 1);
  }
  __syncthreads();
  if (t < 2) {
    int acc = 0;
#pragma unroll
    for (int p = 0; p < NPH; ++p) { s_off[t][p] = acc; acc += s_cnt[t][p]; }
    s_off[t][NPH] = acc;
  }
  __syncthreads();
  if (t < 2 * NPH) s_cnt[t >> 3][t & 7] = 0;
  __syncthreads();

  // Scatter selected indices, bucketed by phase.
  for (int i = t; i < 2 * L; i += 320) {
    const int dd = i < L ? 0 : 1;
    const int idx = s_raw[dd][dd ? i - L : i];
    const int r = idx / RW;
    if ((r & 7) == x) {
      const int pos = s_off[dd][r >> 3] + atomicAdd(&s_cnt[dd][r >> 3], 1);
      s_sel[dd][pos] = idx;
    }
  }
  __syncthreads();

  // Phase loop: all blocks walk ranges x*8+p in the same order.
  float4 a0 = make_float4(0.f, 0.f, 0.f, 0.f);
  float4 a1 = make_float4(0.f, 0.f, 0.f, 0.f);
  if (lane < D4f) {
    for (int p = 0; p < NPH; ++p) {
      {
        const int s = s_off[0][p], e = s_off[0][p + 1];
        for (int i = s + g; i < e; i += 4) {
          const float4 v = reinterpret_cast<const float4*>(
              emb + (size_t)s_sel[0][i] * D)[lane];
          a0.x += v.x; a0.y += v.y; a0.z += v.z; a0.w += v.w;
        }
      }
      {
        const int s = s_off[1][p], e = s_off[1][p + 1];
        for (int i = s + g; i < e; i += 4) {
          const float4 v = reinterpret_cast<const float4*>(
              emb + (size_t)s_sel[1][i] * D)[lane];
          a1.x += v.x; a1.y += v.y; a1.z += v.z; a1.w += v.w;
        }
      }
    }
    sred[g][0][lane] = a0;
    sred[g][1][lane] = a1;
  }
  __syncthreads();

  if (t < 2 * D4f) {
    const int dd = t / D4f, c4 = t - dd * D4f;
    float ax = 0.f, ay = 0.f, az = 0.f, aw = 0.f;
#pragma unroll
    for (int gg = 0; gg < 4; ++gg) {
      const float4 v = sred[gg][dd][c4];
      ax += v.x; ay += v.y; az += v.z; aw += v.w;
    }
    reinterpret_cast<float4*>(partial +
                              (size_t)((j * 2 + dd) * 8 + x) * D)[c4] =
        make_float4(ax, ay, az, aw);
  }
}

// ---------------------------------------------------------------------------
// K2: avg[b] = (sum of 8 octet-partials) / len[b].
// ---------------------------------------------------------------------------
__global__ __launch_bounds__(128) void avg_kernel(
    const float* __restrict__ partial, const int* __restrict__ dlen,
    float* __restrict__ avg) {
  const int b = blockIdx.x;
  const int t = threadIdx.x;
  if (t < D4f) {
    const float4* p =
        reinterpret_cast<const float4*>(partial) + (size_t)b * 8 * D4f + t;
    float4 v[8];
#pragma unroll
    for (int xx = 0; xx < 8; ++xx) v[xx] = p[xx * D4f];
    float ax = 0.f, ay = 0.f, az = 0.f, aw = 0.f;
#pragma unroll
    for (int xx = 0; xx < 8; ++xx) {
      ax += v[xx].x; ay += v[xx].y; az += v[xx].z; aw += v[xx].w;
    }
    const float inv = 1.f / (float)dlen[b];
    reinterpret_cast<float4*>(avg + (size_t)b * D)[t] =
        make_float4(ax * inv, ay * inv, az * inv, aw * inv);
  }
}

// ---------------------------------------------------------------------------
// K3: h1 = relu(avg @ W1 + b1). LDS-staged weights (proven structure).
// ---------------------------------------------------------------------------
__global__ __launch_bounds__(1024) void l1_kernel(
    const float* __restrict__ avg, const float* __restrict__ W1,
    const float* __restrict__ b1, float* __restrict__ h1) {
  const int dq = blockIdx.x;
  const int cq = blockIdx.y;
  const int t = threadIdx.x;

  __shared__ float4 s_avg[16][D4f];
  __shared__ float  s_w[D][32];
  __shared__ float  s_comb[8][16][32];

  for (int o = t; o < D * 8; o += 1024) {
    const int k = o >> 3, c4 = o & 7;
    *reinterpret_cast<float4*>(&s_w[k][c4 * 4]) =
        *reinterpret_cast<const float4*>(W1 + (size_t)k * H + cq * 32 + c4 * 4);
  }
  for (int o = t; o < 16 * D4f; o += 1024) {
    const int doc = o / D4f, c4 = o - doc * D4f;
    s_avg[doc][c4] =
        reinterpret_cast<const float4*>(avg + (size_t)(dq * 16 + doc) * D)[c4];
  }
  __syncthreads();

  {
    const int doc = t & 15;
    const int cg = (t >> 4) & 7;
    const int ks = t >> 7;
    const int nf4 = (ks < 3) ? 10 : 9;
    const int o4 = (ks < 3) ? 10 * ks : 30 + 9 * (ks - 3);
    float ax = 0.f, ay = 0.f, az = 0.f, aw = 0.f;
    for (int j = 0; j < nf4; ++j) {
      const float4 x4 = s_avg[doc][o4 + j];
      const int k = 4 * (o4 + j);
      const float4 w0 = *reinterpret_cast<const float4*>(&s_w[k + 0][cg * 4]);
      const float4 w1 = *reinterpret_cast<const float4*>(&s_w[k + 1][cg * 4]);
      const float4 w2 = *reinterpret_cast<const float4*>(&s_w[k + 2][cg * 4]);
      const float4 w3 = *reinterpret_cast<const float4*>(&s_w[k + 3][cg * 4]);
      ax += x4.x * w0.x + x4.y * w1.x + x4.z * w2.x + x4.w * w3.x;
      ay += x4.x * w0.y + x4.y * w1.y + x4.z * w2.y + x4.w * w3.y;
      az += x4.x * w0.z + x4.y * w1.z + x4.z * w2.z + x4.w * w3.z;
      aw += x4.x * w0.w + x4.y * w1.w + x4.z * w2.w + x4.w * w3.w;
    }
    *reinterpret_cast<float4*>(&s_comb[ks][doc][cg * 4]) =
        make_float4(ax, ay, az, aw);
  }
  __syncthreads();

  if (t < 512) {
    const int dd = t >> 5, col = t & 31;
    float v = b1[cq * 32 + col];
#pragma unroll
    for (int s = 0; s < 8; ++s) v += s_comb[s][dd][col];
    h1[(size_t)(dq * 16 + dd) * H + cq * 32 + col] = fmaxf(v, 0.f);
  }
}

// ---------------------------------------------------------------------------
// K4: h2 = relu(h1 @ W2 + b2).
// ---------------------------------------------------------------------------
__global__ __launch_bounds__(1024) void l2_kernel(
    const float* __restrict__ h1, const float* __restrict__ W2,
    const float* __restrict__ b2, float* __restrict__ h2) {
  const int dq = blockIdx.x;
  const int cq = blockIdx.y;
  const int t = threadIdx.x;

  __shared__ float4 s_x[16][H / 4];
  __shared__ float  s_w[H][32];
  __shared__ float  s_comb[8][16][32];

  for (int o = t; o < H * 8; o += 1024) {
    const int k = o >> 3, c4 = o & 7;
    *reinterpret_cast<float4*>(&s_w[k][c4 * 4]) =
        *reinterpret_cast<const float4*>(W2 + (size_t)k * H + cq * 32 + c4 * 4);
  }
  for (int o = t; o < 16 * (H / 4); o += 1024) {
    const int doc = o >> 7, c4 = o & 127;
    s_x[doc][c4] =
        reinterpret_cast<const float4*>(h1 + (size_t)(dq * 16 + doc) * H)[c4];
  }
  __syncthreads();

  {
    const int doc = t & 15;
    const int cg = (t >> 4) & 7;
    const int ks = t >> 7;
    float ax = 0.f, ay = 0.f, az = 0.f, aw = 0.f;
    for (int j = 0; j < 16; ++j) {
      const int kk = ks * 16 + j;
      const float4 x4 = s_x[doc][kk];
      const int k = 4 * kk;
      const float4 w0 = *reinterpret_cast<const float4*>(&s_w[k + 0][cg * 4]);
      const float4 w1 = *reinterpret_cast<const float4*>(&s_w[k + 1][cg * 4]);
      const float4 w2 = *reinterpret_cast<const float4*>(&s_w[k + 2][cg * 4]);
      const float4 w3 = *reinterpret_cast<const float4*>(&s_w[k + 3][cg * 4]);
      ax += x4.x * w0.x + x4.y * w1.x + x4.z * w2.x + x4.w * w3.x;
      ay += x4.x * w0.y + x4.y * w1.y + x4.z * w2.y + x4.w * w3.y;
      az += x4.x * w0.z + x4.y * w1.z + x4.z * w2.z + x4.w * w3.z;
      aw += x4.x * w0.w + x4.y * w1.w + x4.z * w2.w + x4.w * w3.w;
    }
    *reinterpret_cast<float4*>(&s_comb[ks][doc][cg * 4]) =
        make_float4(ax, ay, az, aw);
  }
  __syncthreads();

  if (t < 512) {
    const int dd = t >> 5, col = t & 31;
    float v = b2[cq * 32 + col];
#pragma unroll
    for (int s = 0; s < 8; ++s) v += s_comb[s][dd][col];
    h2[(size_t)(dq * 16 + dd) * H + cq * 32 + col] = fmaxf(v, 0.f);
  }
}

// ---------------------------------------------------------------------------
// K5: out = h2 @ W3 + b3.
// ---------------------------------------------------------------------------
__global__ __launch_bounds__(64) void head_kernel(
    const float* __restrict__ h2, const float* __restrict__ W3,
    const float* __restrict__ b3, float* __restrict__ out) {
  const int b = blockIdx.x;
  const int l = threadIdx.x;
  float acc[C] = {0.f, 0.f, 0.f, 0.f, 0.f};
#pragma unroll
  for (int i = 0; i < H / 64; ++i) {
    const int h = i * 64 + l;
    const float v = h2[(size_t)b * H + h];
#pragma unroll
    for (int c = 0; c < C; ++c) acc[c] += v * W3[h * C + c];
  }
#pragma unroll
  for (int c = 0; c < C; ++c) {
    float a = acc[c];
#pragma unroll
    for (int off = 32; off > 0; off >>= 1) a += __shfl_down(a, off);
    if (l == 0) out[b * C + c] = a + b3[c];
  }
}

// ---------------------------------------------------------------------------
extern "C" void kernel_launch(void* const* d_in, const int* in_sizes, int n_in,
                              void* d_out, int out_size, void* d_ws,
                              size_t ws_size, hipStream_t stream) {
  const float* emb  = (const float*)d_in[0];
  const float* W1   = (const float*)d_in[1];
  const float* b1   = (const float*)d_in[2];
  const float* W2   = (const float*)d_in[3];
  const float* b2   = (const float*)d_in[4];
  const float* W3   = (const float*)d_in[5];
  const float* b3   = (const float*)d_in[6];
  const int*   docs = (const int*)d_in[7];
  const int*   dlen = (const int*)d_in[8];
  float* out = (float*)d_out;

  float* ws = (float*)d_ws;
  float* partial = ws + WS_PARTIAL;
  float* avg = ws + WS_AVG;
  float* h1  = ws + WS_H1;
  float* h2  = ws + WS_H2;

  gather_phased_kernel<<<B / 2 * 8, 320, 0, stream>>>(emb, docs, partial);
  avg_kernel<<<B, 128, 0, stream>>>(partial, dlen, avg);
  dim3 gl(16, 16);
  l1_kernel<<<gl, 1024, 0, stream>>>(avg, W1, b1, h1);
  l2_kernel<<<gl, 1024, 0, stream>>>(h1, W2, b2, h2);
  head_kernel<<<B, 64, 0, stream>>>(h2, W3, b3, out);
}